// Round 7
// baseline (388.111 us; speedup 1.0000x reference)
//
#include <hip/hip_runtime.h>
#include <math.h>

#define N_TOK 4096
#define DIM   512
#define HID   2048
#define NEXP  8
#define NC    7
#define OUT_MIXED (N_TOK*DIM)   // then [lb, ent], then sel_expert[N,2]
#define TM    48                // tokens per MLP tile (M-tile)
#define TPE   86                // tiles per expert = ceil(4096/48)

typedef __attribute__((ext_vector_type(8))) short bf16x8;
typedef __attribute__((ext_vector_type(4))) float f32x4;

#define XSP 264   // xs row stride (elems): 528B; 2-way bank alias only (free)
#define HSP 264   // hs row stride (elems): same

// ws layout:
//   [0,1024)     int   cpad: per-expert count at [e*32], 128B apart
//   [1024,2048)  float ipad: per-expert importance sum at [e*32]
//   [2048,2052)  int   done-counter (router completion)
//   [4096, +128K)  int   tok_list[8][4096]
//   [ +128K each ) float wt_list[8][4096]
//   OFF_W1S: W1s [8][128 ntile][64 kblk][16 n][8 k]    (16 MB)
//   OFF_W2S: W2s [8][32 ntile][256 kblk][16 n][8 k]    (16 MB)
#define OFF_TOK  4096ull
#define OFF_WT   (OFF_TOK + 131072ull)
#define OFF_XBF  (OFF_WT + 131072ull)          // (unused; kept for ws sizing)
#define OFF_W1S  (OFF_XBF + 4194304ull)
#define OFF_W2S  (OFF_W1S + 16777216ull)
#define WS_REQ   (OFF_W2S + 16777216ull)

__device__ inline unsigned short f2bf(float f) {
  unsigned int u = __builtin_bit_cast(unsigned int, f);
  u = (u + 0x7fffu + ((u >> 16) & 1u)) >> 16;   // RNE
  return (unsigned short)u;
}

// ---------------------------------------------------------------------------
// Fused prep kernel:
//   blocks [0,256)        : router (+ last-block finalize of lb/ent)
//   blocks [256,1280)     : convert W1 -> W1s
//   blocks [1280,2304)    : convert W2 -> W2s
// ---------------------------------------------------------------------------
__device__ void dev_convert_w(const float* __restrict__ W,
                              unsigned int* __restrict__ Ws,
                              int K, int Nm, int tiles_n, int b,
                              unsigned short (*lds)[264])
{
  const int tid = threadIdx.x;
  const int e  = b >> 7;
  const int rm = b & 127;
  const int tk = rm / tiles_n;
  const int tn = rm - tk * tiles_n;

  const float* src = W + ((size_t)e * K + tk * 32) * Nm + tn * 256;
  // 32 rows x 256 cols = 2048 float4 units; float4 loads (16B/lane)
#pragma unroll
  for (int it = 0; it < 8; ++it) {
    const int g   = it * 256 + tid;
    const int row = g >> 6, c4 = g & 63;
    const float4 v = *(const float4*)(src + (size_t)row * Nm + c4 * 4);
    ushort4 o;
    o.x = f2bf(v.x); o.y = f2bf(v.y); o.z = f2bf(v.z); o.w = f2bf(v.w);
    *(ushort4*)(&lds[row][c4 * 4]) = o;
  }
  __syncthreads();

  const int ntiles = Nm >> 4, kblks = K >> 3;
#pragma unroll
  for (int it = 0; it < 16; ++it) {
    const int uid   = it * 256 + tid;
    const int nt_l  = uid >> 8;
    const int r     = uid & 255;
    const int kb_l  = r >> 6;
    const int u     = r & 63;
    const int n_lo  = u >> 2;
    const int k_hf  = u & 3;
    const int d_l   = kb_l * 8 + k_hf * 2;
    const int h_l   = nt_l * 16 + n_lo;
    const unsigned int s0 = lds[d_l][h_l], s1 = lds[d_l + 1][h_l];
    const int nt_g = tn * 16 + nt_l;
    const int kb_g = tk * 4 + kb_l;
    const size_t frag = ((size_t)e * ntiles + nt_g) * kblks + kb_g;
    Ws[frag * 64 + n_lo * 4 + k_hf] = s0 | (s1 << 16);
  }
}

__global__ __launch_bounds__(256) void prep_kernel(
    const float* __restrict__ x, const float* __restrict__ rW,
    const float* __restrict__ rb,
    const float* __restrict__ W1, const float* __restrict__ W2,
    float* __restrict__ out,
    int* __restrict__ cpad, float* __restrict__ ipad, int* __restrict__ done,
    int* __restrict__ tok_list, float* __restrict__ wt_list,
    unsigned int* __restrict__ W1s, unsigned int* __restrict__ W2s)
{
  __shared__ unsigned short clds[32][264];
  __shared__ float imp_loc[8];
  __shared__ int   cnt_loc[8];
  __shared__ int   ltok[8][32];
  __shared__ float lwt[8][32];
  __shared__ int   base_s[8];

  const int tid = threadIdx.x;
  const int blk = blockIdx.x;

  if (blk >= 256) {
    const int b = blk - 256;
    if (b < 1024) dev_convert_w(W1, W1s, DIM, HID, 8, b, clds);
    else          dev_convert_w(W2, W2s, HID, DIM, 2, b - 1024, clds);
    return;
  }

  // ---- router: 16 tokens per block, 4 per wave
  if (tid < 8) { imp_loc[tid] = 0.f; cnt_loc[tid] = 0; }
  __syncthreads();
  const int wave = tid >> 6, lane = tid & 63;

  for (int it = 0; it < 4; ++it) {
    const int t = blk * 16 + wave * 4 + it;
    float xv[8];
#pragma unroll
    for (int j = 0; j < 8; ++j) xv[j] = x[(size_t)t*DIM + lane + 64*j];
    float lg[NC];
#pragma unroll
    for (int e = 0; e < NC; ++e) {
      float s = 0.f;
#pragma unroll
      for (int j = 0; j < 8; ++j) s += xv[j] * rW[(lane + 64*j)*NC + e];
      lg[e] = s;
    }
#pragma unroll
    for (int e = 0; e < NC; ++e) {
      float s = lg[e];
#pragma unroll
      for (int off = 32; off > 0; off >>= 1) s += __shfl_xor(s, off, 64);
      lg[e] = s + rb[e];
    }
    int i1 = 0; float l1 = lg[0];
#pragma unroll
    for (int e = 1; e < NC; ++e) { if (lg[e] > l1) { l1 = lg[e]; i1 = e; } }
    int i2 = -1; float l2 = -3.4e38f;
#pragma unroll
    for (int e = 0; e < NC; ++e) { if (e != i1 && lg[e] > l2) { l2 = lg[e]; i2 = e; } }

    const float ed = expf(l2 - l1);
    const float g1 = 1.f/(1.f+ed), g2 = ed/(1.f+ed);

    float p[NC]; float ssum = 0.f;
#pragma unroll
    for (int e = 0; e < NC; ++e) { p[e] = expf(lg[e] - l1); ssum += p[e]; }
    const float inv = 1.f/ssum;

    if (lane == 0) {
#pragma unroll
      for (int e = 0; e < NC; ++e) atomicAdd(&imp_loc[e], p[e]*inv);
      out[OUT_MIXED + 2 + 2*t]     = (float)(i1 + 1);
      out[OUT_MIXED + 2 + 2*t + 1] = (float)(i2 + 1);
      const int e1 = i1 + 1, e2 = i2 + 1;
      int p1 = atomicAdd(&cnt_loc[e1], 1);
      ltok[e1][p1] = t;  lwt[e1][p1] = (2.f/3.f)*g1;
      int p2 = atomicAdd(&cnt_loc[e2], 1);
      ltok[e2][p2] = t;  lwt[e2][p2] = (2.f/3.f)*g2;
    }
  }
  __syncthreads();

  if (tid >= 1 && tid < 8)
    base_s[tid] = atomicAdd(&cpad[tid * 32], cnt_loc[tid]);
  if (tid < NC)
    atomicAdd(&ipad[(tid + 1) * 32], imp_loc[tid]);   // expert e=tid+1 slot
  __syncthreads();

  {
    const int e = tid >> 5, i = tid & 31;
    if (e >= 1 && i < cnt_loc[e]) {
      const int dst = e * N_TOK + base_s[e] + i;
      tok_list[dst] = ltok[e][i];
      wt_list [dst] = lwt[e][i];
    }
  }

  // ---- last router block computes aux losses
  if (tid == 0) {
    __threadfence();
    const int old = atomicAdd(done, 1);
    if (old == 255) {
      __threadfence();
      float lb = 0.f, ent = 0.f;
      for (int e = 0; e < NC; ++e) {
        float p = ipad[(e + 1) * 32] * (1.f/(float)N_TOK);
        float d = p - (1.f/(float)NC);
        lb += d*d;
        ent -= p * logf(fmaxf(p, 1e-8f));
      }
      out[OUT_MIXED]     = lb * (1.f/(float)NC);
      out[OUT_MIXED + 1] = ent;
    }
  }
}

// ---------------------------------------------------------------------------
// MFMA grouped MLP: block = (expert, 48-token tile, chunk-half), 8 waves.
// M=48: 3 A-fragments per B-load (intensity 24 FLOP/L2-byte). xs staged per
// K-half (fp32 x converted to bf16 in-staging). Grid [e][tile][half].
// ---------------------------------------------------------------------------
__global__ __launch_bounds__(512) void moe_mlp_mfma(
    const float* __restrict__ x,
    const unsigned short* __restrict__ W1s,
    const unsigned short* __restrict__ W2s,
    const float* __restrict__ b1, const float* __restrict__ b2,
    const float* __restrict__ fixed_w,
    const int* __restrict__ cpad, const int* __restrict__ tok_list,
    const float* __restrict__ wt_list, float* __restrict__ out)
{
  const int e    = blockIdx.x / (TPE * 2);   // [e][tile][half], half fastest
  const int r    = blockIdx.x % (TPE * 2);
  const int tile = r >> 1;
  const int half = r & 1;
  const int cnt  = (e == 0) ? N_TOK : cpad[e * 32];
  const int start = tile * TM;
  if (start >= cnt) return;   // uniform per block

  __shared__ __align__(16) unsigned short xs[TM * XSP];  // 25344 B
  __shared__ __align__(16) unsigned short hs[TM * HSP];  // 25344 B
  __shared__ int   tok_s[TM];
  __shared__ float wt_s[TM];

  const int tid = threadIdx.x;
  if (tid < TM) {
    int idx = start + tid; int t = 0; float w = 0.f;
    if (idx < cnt) {
      if (e == 0) { t = idx; w = (1.f/3.f) * fixed_w[0]; }
      else        { t = tok_list[e*N_TOK + idx]; w = wt_list[e*N_TOK + idx]; }
    }
    tok_s[tid] = t; wt_s[tid] = w;
  }
  __syncthreads();

  const int lane = tid & 63;
  const int w    = tid >> 6;          // 0..7
  const int l15  = lane & 15;
  const int q    = lane >> 4;

  const unsigned short* W1e = W1s + (size_t)e * 128 * 64 * 128;
  const unsigned short* W2e = W2s + (size_t)e * 32 * 256 * 128;

  f32x4 yacc[3][4];
#pragma unroll
  for (int mi = 0; mi < 3; ++mi)
#pragma unroll
    for (int t = 0; t < 4; ++t) yacc[mi][t] = (f32x4){0.f, 0.f, 0.f, 0.f};

  for (int c = half * 4; c < half * 4 + 4; ++c) {
    const int nt_base = c * 16 + w * 2;
    f32x4 hacc[3][2];
#pragma unroll
    for (int mi = 0; mi < 3; ++mi)
#pragma unroll
      for (int t = 0; t < 2; ++t) hacc[mi][t] = (f32x4){0.f, 0.f, 0.f, 0.f};

#pragma unroll
    for (int kh = 0; kh < 2; ++kh) {
      // ---- stage xs[48][256] for this K-half, converting fp32 -> bf16
      for (int i = tid; i < TM * 32; i += 512) {
        const int m = i >> 5, cb = i & 31;
        const float* src = x + (size_t)tok_s[m] * DIM + kh * 256 + cb * 8;
        const float4 v0 = *(const float4*)(src);
        const float4 v1 = *(const float4*)(src + 4);
        ushort4 o0, o1;
        o0.x=f2bf(v0.x); o0.y=f2bf(v0.y); o0.z=f2bf(v0.z); o0.w=f2bf(v0.w);
        o1.x=f2bf(v1.x); o1.y=f2bf(v1.y); o1.z=f2bf(v1.z); o1.w=f2bf(v1.w);
        *(ushort4*)(xs + m * XSP + cb * 8)     = o0;
        *(ushort4*)(xs + m * XSP + cb * 8 + 4) = o1;
      }
      __syncthreads();   // xs ready

      // ---- phase 1 partial: 8 ksteps of this K-half
#pragma unroll 4
      for (int s = 0; s < 8; ++s) {
        const bf16x8 a0 = *(const bf16x8*)(xs + l15 * XSP + s * 32 + q * 8);
        const bf16x8 a1 = *(const bf16x8*)(xs + (16 + l15) * XSP + s * 32 + q * 8);
        const bf16x8 a2 = *(const bf16x8*)(xs + (32 + l15) * XSP + s * 32 + q * 8);
        const int kblk = (kh * 8 + s) * 4 + q;
#pragma unroll
        for (int t = 0; t < 2; ++t) {
          const bf16x8 b = *(const bf16x8*)(
              W1e + (((size_t)(nt_base + t) * 64) + kblk) * 128 + l15 * 8);
          hacc[0][t] = __builtin_amdgcn_mfma_f32_16x16x32_bf16(a0, b, hacc[0][t], 0, 0, 0);
          hacc[1][t] = __builtin_amdgcn_mfma_f32_16x16x32_bf16(a1, b, hacc[1][t], 0, 0, 0);
          hacc[2][t] = __builtin_amdgcn_mfma_f32_16x16x32_bf16(a2, b, hacc[2][t], 0, 0, 0);
        }
      }
      if (kh == 0) __syncthreads();   // guard xs restage
    }

    // ---- bias + relu -> hs (rows = token m, cols = local hidden n)
#pragma unroll
    for (int t = 0; t < 2; ++t) {
      const float bv = b1[e * HID + (nt_base + t) * 16 + l15];
      const int col = w * 32 + t * 16 + l15;
#pragma unroll
      for (int mi = 0; mi < 3; ++mi)
#pragma unroll
        for (int reg = 0; reg < 4; ++reg)
          hs[(mi * 16 + q * 4 + reg) * HSP + col] =
              f2bf(fmaxf(hacc[mi][t][reg] + bv, 0.f));
    }
    __syncthreads();   // hs ready (prev phase2 done via trailing sync)

    // ---- phase 2: wave owns 4 output n-tiles (64 of 512 dims), K=256
#pragma unroll 2
    for (int s = 0; s < 8; ++s) {
      const bf16x8 a0 = *(const bf16x8*)(hs + l15 * HSP + s * 32 + q * 8);
      const bf16x8 a1 = *(const bf16x8*)(hs + (16 + l15) * HSP + s * 32 + q * 8);
      const bf16x8 a2 = *(const bf16x8*)(hs + (32 + l15) * HSP + s * 32 + q * 8);
      const int kblk = c * 32 + s * 4 + q;
#pragma unroll
      for (int t = 0; t < 4; ++t) {
        const bf16x8 b = *(const bf16x8*)(
            W2e + (((size_t)(w * 4 + t) * 256) + kblk) * 128 + l15 * 8);
        yacc[0][t] = __builtin_amdgcn_mfma_f32_16x16x32_bf16(a0, b, yacc[0][t], 0, 0, 0);
        yacc[1][t] = __builtin_amdgcn_mfma_f32_16x16x32_bf16(a1, b, yacc[1][t], 0, 0, 0);
        yacc[2][t] = __builtin_amdgcn_mfma_f32_16x16x32_bf16(a2, b, yacc[2][t], 0, 0, 0);
      }
    }
    __syncthreads();   // hs consumed + xs free for next chunk
  }

  // ---- epilogue: out[tok] += wt * (y_half + b2*(half==0))
#pragma unroll
  for (int t = 0; t < 4; ++t) {
    const int d = (w * 4 + t) * 16 + l15;
    const float b2v = half ? 0.f : b2[e * DIM + d];
#pragma unroll
    for (int mi = 0; mi < 3; ++mi)
#pragma unroll
      for (int reg = 0; reg < 4; ++reg) {
        const int m = mi * 16 + q * 4 + reg;
        atomicAdd(&out[(size_t)tok_s[m] * DIM + d], wt_s[m] * (yacc[mi][t][reg] + b2v));
      }
  }
}

// ---------------------------------------------------------------------------
// fp32 fallback path (standalone router + mlp) — only if ws_size < WS_REQ
// ---------------------------------------------------------------------------
__global__ __launch_bounds__(256) void router_only(
    const float* __restrict__ x, const float* __restrict__ rW,
    const float* __restrict__ rb, float* __restrict__ out,
    int* __restrict__ cpad, float* __restrict__ ipad, int* __restrict__ done,
    int* __restrict__ tok_list, float* __restrict__ wt_list)
{
  __shared__ float imp_loc[8];
  __shared__ int   cnt_loc[8];
  __shared__ int   ltok[8][32];
  __shared__ float lwt[8][32];
  __shared__ int   base_s[8];

  const int tid = threadIdx.x;
  if (tid < 8) { imp_loc[tid] = 0.f; cnt_loc[tid] = 0; }
  __syncthreads();
  const int wave = tid >> 6, lane = tid & 63;

  for (int it = 0; it < 4; ++it) {
    const int t = blockIdx.x * 16 + wave * 4 + it;
    float xv[8];
#pragma unroll
    for (int j = 0; j < 8; ++j) xv[j] = x[(size_t)t*DIM + lane + 64*j];
    float lg[NC];
#pragma unroll
    for (int e = 0; e < NC; ++e) {
      float s = 0.f;
#pragma unroll
      for (int j = 0; j < 8; ++j) s += xv[j] * rW[(lane + 64*j)*NC + e];
      lg[e] = s;
    }
#pragma unroll
    for (int e = 0; e < NC; ++e) {
      float s = lg[e];
#pragma unroll
      for (int off = 32; off > 0; off >>= 1) s += __shfl_xor(s, off, 64);
      lg[e] = s + rb[e];
    }
    int i1 = 0; float l1 = lg[0];
#pragma unroll
    for (int e = 1; e < NC; ++e) { if (lg[e] > l1) { l1 = lg[e]; i1 = e; } }
    int i2 = -1; float l2 = -3.4e38f;
#pragma unroll
    for (int e = 0; e < NC; ++e) { if (e != i1 && lg[e] > l2) { l2 = lg[e]; i2 = e; } }
    const float ed = expf(l2 - l1);
    const float g1 = 1.f/(1.f+ed), g2 = ed/(1.f+ed);
    float p[NC]; float ssum = 0.f;
#pragma unroll
    for (int e = 0; e < NC; ++e) { p[e] = expf(lg[e] - l1); ssum += p[e]; }
    const float inv = 1.f/ssum;
    if (lane == 0) {
#pragma unroll
      for (int e = 0; e < NC; ++e) atomicAdd(&imp_loc[e], p[e]*inv);
      out[OUT_MIXED + 2 + 2*t]     = (float)(i1 + 1);
      out[OUT_MIXED + 2 + 2*t + 1] = (float)(i2 + 1);
      const int e1 = i1 + 1, e2 = i2 + 1;
      int p1 = atomicAdd(&cnt_loc[e1], 1);
      ltok[e1][p1] = t;  lwt[e1][p1] = (2.f/3.f)*g1;
      int p2 = atomicAdd(&cnt_loc[e2], 1);
      ltok[e2][p2] = t;  lwt[e2][p2] = (2.f/3.f)*g2;
    }
  }
  __syncthreads();
  if (tid >= 1 && tid < 8)
    base_s[tid] = atomicAdd(&cpad[tid * 32], cnt_loc[tid]);
  if (tid < NC)
    atomicAdd(&ipad[(tid + 1) * 32], imp_loc[tid]);
  __syncthreads();
  {
    const int e = tid >> 5, i = tid & 31;
    if (e >= 1 && i < cnt_loc[e]) {
      const int dst = e * N_TOK + base_s[e] + i;
      tok_list[dst] = ltok[e][i];
      wt_list [dst] = lwt[e][i];
    }
  }
  if (tid == 0) {
    __threadfence();
    const int old = atomicAdd(done, 1);
    if (old == 255) {
      __threadfence();
      float lb = 0.f, ent = 0.f;
      for (int e = 0; e < NC; ++e) {
        float p = ipad[(e + 1) * 32] * (1.f/(float)N_TOK);
        float d = p - (1.f/(float)NC);
        lb += d*d;
        ent -= p * logf(fmaxf(p, 1e-8f));
      }
      out[OUT_MIXED]     = lb * (1.f/(float)NC);
      out[OUT_MIXED + 1] = ent;
    }
  }
}

__global__ __launch_bounds__(256) void moe_mlp_kernel(
    const float* __restrict__ x,
    const float* __restrict__ W1, const float* __restrict__ b1,
    const float* __restrict__ W2, const float* __restrict__ b2,
    const float* __restrict__ fixed_w,
    const int* __restrict__ cpad, const int* __restrict__ tok_list,
    const float* __restrict__ wt_list, float* __restrict__ out)
{
  const int e    = blockIdx.x >> 8;
  const int tile = blockIdx.x & 255;
  const int cnt  = (e == 0) ? N_TOK : cpad[e * 32];
  const int start = tile * 16;
  if (start >= cnt) return;

  __shared__ float xs[DIM][17];
  __shared__ float hs2[256][17];
  __shared__ int   tok_s[16];
  __shared__ float wt_s[16];

  const int tid = threadIdx.x;
  if (tid < 16) {
    int idx = start + tid; int t = 0; float w = 0.f;
    if (idx < cnt) {
      if (e == 0) { t = idx; w = (1.f/3.f) * fixed_w[0]; }
      else        { t = tok_list[e*N_TOK + idx]; w = wt_list[e*N_TOK + idx]; }
    }
    tok_s[tid] = t; wt_s[tid] = w;
  }
  __syncthreads();

  for (int i = tid; i < 16*DIM; i += 256) {
    const int m = i >> 9, d = i & (DIM-1);
    xs[d][m] = x[(size_t)tok_s[m]*DIM + d];
  }

  const int r  = tid & 63;
  const int m0 = (tid >> 6) * 4;
  const float* W1e = W1 + (size_t)e * DIM * HID;
  const float* W2e = W2 + (size_t)e * HID * DIM;
  const float* b1e = b1 + e * HID;

  float yacc[4][8];
#pragma unroll
  for (int j = 0; j < 4; ++j)
#pragma unroll
    for (int i = 0; i < 8; ++i) yacc[j][i] = 0.f;

  __syncthreads();

  for (int c = 0; c < 8; ++c) {
    const int k0 = c * 256;
    float bv[4];
#pragma unroll
    for (int i = 0; i < 4; ++i) bv[i] = b1e[k0 + r + 64*i];
    float hacc[4][4];
#pragma unroll
    for (int j = 0; j < 4; ++j)
#pragma unroll
      for (int i = 0; i < 4; ++i) hacc[j][i] = bv[i];
#pragma unroll 2
    for (int d = 0; d < DIM; ++d) {
      float wv[4];
#pragma unroll
      for (int i = 0; i < 4; ++i) wv[i] = W1e[(size_t)d*HID + k0 + r + 64*i];
      float xv[4];
#pragma unroll
      for (int j = 0; j < 4; ++j) xv[j] = xs[d][m0+j];
#pragma unroll
      for (int j = 0; j < 4; ++j)
#pragma unroll
        for (int i = 0; i < 4; ++i) hacc[j][i] += xv[j]*wv[i];
    }
#pragma unroll
    for (int i = 0; i < 4; ++i)
#pragma unroll
      for (int j = 0; j < 4; ++j) hs2[r + 64*i][m0+j] = fmaxf(hacc[j][i], 0.f);
    __syncthreads();

#pragma unroll 2
    for (int k = 0; k < 256; ++k) {
      float wv2[8];
#pragma unroll
      for (int i = 0; i < 8; ++i) wv2[i] = W2e[(size_t)(k0+k)*DIM + r + 64*i];
      float hv[4];
#pragma unroll
      for (int j = 0; j < 4; ++j) hv[j] = hs2[k][m0+j];
#pragma unroll
      for (int j = 0; j < 4; ++j)
#pragma unroll
        for (int i = 0; i < 8; ++i) yacc[j][i] += hv[j]*wv2[i];
    }
    __syncthreads();
  }

#pragma unroll
  for (int i = 0; i < 8; ++i) {
    const int d = r + 64*i;
    const float b2v = b2[e*DIM + d];
#pragma unroll
    for (int j = 0; j < 4; ++j) {
      const int m = m0 + j;
      atomicAdd(&out[(size_t)tok_s[m]*DIM + d], wt_s[m]*(yacc[j][i] + b2v));
    }
  }
}

extern "C" void kernel_launch(void* const* d_in, const int* in_sizes, int n_in,
                              void* d_out, int out_size, void* d_ws, size_t ws_size,
                              hipStream_t stream)
{
  const float* x  = (const float*)d_in[0];
  const float* rW = (const float*)d_in[1];
  const float* rb = (const float*)d_in[2];
  const float* W1 = (const float*)d_in[3];
  const float* b1 = (const float*)d_in[4];
  const float* W2 = (const float*)d_in[5];
  const float* b2 = (const float*)d_in[6];
  const float* fw = (const float*)d_in[7];
  float* out = (float*)d_out;

  int*   cpad     = (int*)d_ws;                          // [e*32], 128B apart
  float* ipad     = (float*)((char*)d_ws + 1024);
  int*   done     = (int*)((char*)d_ws + 2048);
  int*   tok_list = (int*)((char*)d_ws + OFF_TOK);
  float* wt_list  = (float*)((char*)d_ws + OFF_WT);

  hipMemsetAsync(d_ws, 0, 4096, stream);                 // counters + done
  hipMemsetAsync(d_out, 0, (size_t)OUT_MIXED*4, stream); // mixed accumulator

  if (ws_size >= WS_REQ) {
    unsigned int* W1s = (unsigned int*)((char*)d_ws + OFF_W1S);
    unsigned int* W2s = (unsigned int*)((char*)d_ws + OFF_W2S);
    prep_kernel<<<2304, 256, 0, stream>>>(x, rW, rb, W1, W2, out,
                                          cpad, ipad, done, tok_list, wt_list,
                                          W1s, W2s);
    moe_mlp_mfma<<<NEXP*TPE*2, 512, 0, stream>>>(x, (const unsigned short*)W1s,
                                                 (const unsigned short*)W2s, b1, b2, fw,
                                                 cpad, tok_list, wt_list, out);
  } else {
    router_only<<<256, 256, 0, stream>>>(x, rW, rb, out, cpad, ipad, done,
                                         tok_list, wt_list);
    moe_mlp_kernel<<<NEXP*256, 256, 0, stream>>>(x, W1, b1, W2, b2, fw,
                                                 cpad, tok_list, wt_list, out);
  }
}

// Round 8
// 288.032 us; speedup vs baseline: 1.3475x; 1.3475x over previous
//
#include <hip/hip_runtime.h>
#include <math.h>

#define N_TOK 4096
#define DIM   512
#define HID   2048
#define NEXP  8
#define NC    7
#define OUT_MIXED (N_TOK*DIM)   // then [lb, ent], then sel_expert[N,2]
#define TM    48                // tokens per MLP tile (M-tile)
#define TPE   86                // tiles per expert = ceil(4096/48)

typedef __attribute__((ext_vector_type(8))) short bf16x8;
typedef __attribute__((ext_vector_type(4))) float f32x4;

#define XSP 520   // xs row stride (elems): 1040B -> 2-way bank alias only (free)
#define HSP 136   // hs row stride (elems): 272B = 17x16B, rows spread 4 banks

// ws layout:
//   [0,1024)     int   cpad: per-expert count at [e*32], 128B apart
//   [1024,2048)  float ipad: per-expert importance sum at [e*32]
//   [2048,2052)  int   done-counter (router completion)
//   [4096, +128K)  int   tok_list[8][4096]
//   [ +128K each ) float wt_list[8][4096]
//   OFF_XBF: xbf [4096][512] bf16                      (4 MB)
//   OFF_W1S: W1s [8][128 ntile][64 kblk][16 n][8 k]    (16 MB)
//   OFF_W2S: W2s [8][32 ntile][256 kblk][16 n][8 k]    (16 MB)
#define OFF_TOK  4096ull
#define OFF_WT   (OFF_TOK + 131072ull)
#define OFF_XBF  (OFF_WT + 131072ull)
#define OFF_W1S  (OFF_XBF + 4194304ull)
#define OFF_W2S  (OFF_W1S + 16777216ull)
#define WS_REQ   (OFF_W2S + 16777216ull)

__device__ inline unsigned short f2bf(float f) {
  unsigned int u = __builtin_bit_cast(unsigned int, f);
  u = (u + 0x7fffu + ((u >> 16) & 1u)) >> 16;   // RNE
  return (unsigned short)u;
}

// ---------------------------------------------------------------------------
// Fused prep kernel:
//   blocks [0,256)       : router (+ last-block finalize of lb/ent)
//   blocks [256,768)     : zero out[0, OUT_MIXED)
//   blocks [768,1792)    : convert x  -> xbf
//   blocks [1792,2816)   : convert W1 -> W1s
//   blocks [2816,3840)   : convert W2 -> W2s
// ---------------------------------------------------------------------------
__device__ void dev_convert_w(const float* __restrict__ W,
                              unsigned int* __restrict__ Ws,
                              int K, int Nm, int tiles_n, int b,
                              unsigned short (*lds)[264])
{
  const int tid = threadIdx.x;
  const int e  = b >> 7;
  const int rm = b & 127;
  const int tk = rm / tiles_n;
  const int tn = rm - tk * tiles_n;

  const float* src = W + ((size_t)e * K + tk * 32) * Nm + tn * 256;
#pragma unroll
  for (int it = 0; it < 8; ++it) {
    const int g   = it * 256 + tid;
    const int row = g >> 6, c4 = g & 63;
    const float4 v = *(const float4*)(src + (size_t)row * Nm + c4 * 4);
    ushort4 o;
    o.x = f2bf(v.x); o.y = f2bf(v.y); o.z = f2bf(v.z); o.w = f2bf(v.w);
    *(ushort4*)(&lds[row][c4 * 4]) = o;
  }
  __syncthreads();

  const int ntiles = Nm >> 4, kblks = K >> 3;
#pragma unroll
  for (int it = 0; it < 16; ++it) {
    const int uid   = it * 256 + tid;
    const int nt_l  = uid >> 8;
    const int r     = uid & 255;
    const int kb_l  = r >> 6;
    const int u     = r & 63;
    const int n_lo  = u >> 2;
    const int k_hf  = u & 3;
    const int d_l   = kb_l * 8 + k_hf * 2;
    const int h_l   = nt_l * 16 + n_lo;
    const unsigned int s0 = lds[d_l][h_l], s1 = lds[d_l + 1][h_l];
    const int nt_g = tn * 16 + nt_l;
    const int kb_g = tk * 4 + kb_l;
    const size_t frag = ((size_t)e * ntiles + nt_g) * kblks + kb_g;
    Ws[frag * 64 + n_lo * 4 + k_hf] = s0 | (s1 << 16);
  }
}

__global__ __launch_bounds__(256) void prep_kernel(
    const float* __restrict__ x, const float* __restrict__ rW,
    const float* __restrict__ rb,
    const float* __restrict__ W1, const float* __restrict__ W2,
    float* __restrict__ out,
    int* __restrict__ cpad, float* __restrict__ ipad, int* __restrict__ done,
    int* __restrict__ tok_list, float* __restrict__ wt_list,
    unsigned short* __restrict__ xbf,
    unsigned int* __restrict__ W1s, unsigned int* __restrict__ W2s)
{
  __shared__ unsigned short clds[32][264];
  __shared__ float imp_loc[8];
  __shared__ int   cnt_loc[8];
  __shared__ int   ltok[8][32];
  __shared__ float lwt[8][32];
  __shared__ int   base_s[8];

  const int tid = threadIdx.x;
  const int blk = blockIdx.x;

  if (blk >= 256) {
    const int b = blk - 256;
    if (b < 512) {
      // ---- zero the mixed-output accumulator: 16 floats per thread
      float* p = out + ((size_t)b * 256 + tid) * 16;
      const float4 z = {0.f, 0.f, 0.f, 0.f};
      *(float4*)(p)      = z;  *(float4*)(p + 4)  = z;
      *(float4*)(p + 8)  = z;  *(float4*)(p + 12) = z;
    } else if (b < 1536) {
      // ---- convert_x: 8 elems per thread
      const int g = (b - 512) * 256 + tid;
      const float* src = x + (size_t)g * 8;
      unsigned short tmp[8];
#pragma unroll
      for (int j = 0; j < 8; ++j) tmp[j] = f2bf(src[j]);
      *(uint4*)(xbf + (size_t)g * 8) = *(const uint4*)tmp;
    } else if (b < 2560) {
      dev_convert_w(W1, W1s, DIM, HID, 8, b - 1536, clds);
    } else {
      dev_convert_w(W2, W2s, HID, DIM, 2, b - 2560, clds);
    }
    return;
  }

  // ---- router: 16 tokens per block, 4 per wave
  if (tid < 8) { imp_loc[tid] = 0.f; cnt_loc[tid] = 0; }
  __syncthreads();
  const int wave = tid >> 6, lane = tid & 63;

  // hoist rW into registers: lane owns dims d = j*256 + lane*4 + k
  // rows (j*256+lane*4 .. +3) = 28 consecutive floats at rW + j*1792 + lane*28
  float rw[2][4][NC];
#pragma unroll
  for (int j = 0; j < 2; ++j) {
    const float* p = rW + j * 1792 + lane * 28;
    float tmp[28];
#pragma unroll
    for (int u = 0; u < 7; ++u) *(float4*)(tmp + u * 4) = *(const float4*)(p + u * 4);
#pragma unroll
    for (int k = 0; k < 4; ++k)
#pragma unroll
      for (int e = 0; e < NC; ++e) rw[j][k][e] = tmp[k * 7 + e];
  }

  for (int it = 0; it < 4; ++it) {
    const int t = blk * 16 + wave * 4 + it;
    const float4 xa = *(const float4*)(x + (size_t)t * DIM + lane * 4);
    const float4 xb = *(const float4*)(x + (size_t)t * DIM + 256 + lane * 4);
    const float xv[2][4] = {{xa.x, xa.y, xa.z, xa.w}, {xb.x, xb.y, xb.z, xb.w}};
    float lg[NC];
#pragma unroll
    for (int e = 0; e < NC; ++e) {
      float s = 0.f;
#pragma unroll
      for (int j = 0; j < 2; ++j)
#pragma unroll
        for (int k = 0; k < 4; ++k) s += xv[j][k] * rw[j][k][e];
      lg[e] = s;
    }
#pragma unroll
    for (int e = 0; e < NC; ++e) {
      float s = lg[e];
#pragma unroll
      for (int off = 32; off > 0; off >>= 1) s += __shfl_xor(s, off, 64);
      lg[e] = s + rb[e];
    }
    int i1 = 0; float l1 = lg[0];
#pragma unroll
    for (int e = 1; e < NC; ++e) { if (lg[e] > l1) { l1 = lg[e]; i1 = e; } }
    int i2 = -1; float l2 = -3.4e38f;
#pragma unroll
    for (int e = 0; e < NC; ++e) { if (e != i1 && lg[e] > l2) { l2 = lg[e]; i2 = e; } }

    const float ed = expf(l2 - l1);
    const float g1 = 1.f/(1.f+ed), g2 = ed/(1.f+ed);

    float p[NC]; float ssum = 0.f;
#pragma unroll
    for (int e = 0; e < NC; ++e) { p[e] = expf(lg[e] - l1); ssum += p[e]; }
    const float inv = 1.f/ssum;

    if (lane == 0) {
#pragma unroll
      for (int e = 0; e < NC; ++e) atomicAdd(&imp_loc[e], p[e]*inv);
      out[OUT_MIXED + 2 + 2*t]     = (float)(i1 + 1);
      out[OUT_MIXED + 2 + 2*t + 1] = (float)(i2 + 1);
      const int e1 = i1 + 1, e2 = i2 + 1;
      int p1 = atomicAdd(&cnt_loc[e1], 1);
      ltok[e1][p1] = t;  lwt[e1][p1] = (2.f/3.f)*g1;
      int p2 = atomicAdd(&cnt_loc[e2], 1);
      ltok[e2][p2] = t;  lwt[e2][p2] = (2.f/3.f)*g2;
    }
  }
  __syncthreads();

  if (tid >= 1 && tid < 8)
    base_s[tid] = atomicAdd(&cpad[tid * 32], cnt_loc[tid]);
  if (tid < NC)
    atomicAdd(&ipad[(tid + 1) * 32], imp_loc[tid]);   // expert e=tid+1 slot
  __syncthreads();

  {
    const int e = tid >> 5, i = tid & 31;
    if (e >= 1 && i < cnt_loc[e]) {
      const int dst = e * N_TOK + base_s[e] + i;
      tok_list[dst] = ltok[e][i];
      wt_list [dst] = lwt[e][i];
    }
  }

  // ---- last router block computes aux losses
  if (tid == 0) {
    __threadfence();
    const int old = atomicAdd(done, 1);
    if (old == 255) {
      __threadfence();
      float lb = 0.f, ent = 0.f;
      for (int e = 0; e < NC; ++e) {
        float p = ipad[(e + 1) * 32] * (1.f/(float)N_TOK);
        float d = p - (1.f/(float)NC);
        lb += d*d;
        ent -= p * logf(fmaxf(p, 1e-8f));
      }
      out[OUT_MIXED]     = lb * (1.f/(float)NC);
      out[OUT_MIXED + 1] = ent;
    }
  }
}

// ---------------------------------------------------------------------------
// MFMA grouped MLP: block = (expert, 48-token tile, chunk-half), 8 waves.
// M=48 (3 A-frags per B-load, 24 FLOP/byte on the weight stream). Full-K xs
// staged ONCE (no restaging). Hidden processed in 16 chunks of 128 cols
// (8 per half) so hs fits: LDS = 49.9K + 13K = 63.4 KB -> 2 blocks/CU.
// ---------------------------------------------------------------------------
__global__ __launch_bounds__(512, 4) void moe_mlp_mfma(
    const unsigned short* __restrict__ xbf,
    const unsigned short* __restrict__ W1s,
    const unsigned short* __restrict__ W2s,
    const float* __restrict__ b1, const float* __restrict__ b2,
    const float* __restrict__ fixed_w,
    const int* __restrict__ cpad, const int* __restrict__ tok_list,
    const float* __restrict__ wt_list, float* __restrict__ out)
{
  const int e    = blockIdx.x / (TPE * 2);   // [e][tile][half], half fastest
  const int r    = blockIdx.x % (TPE * 2);
  const int tile = r >> 1;
  const int half = r & 1;
  const int cnt  = (e == 0) ? N_TOK : cpad[e * 32];
  const int start = tile * TM;
  if (start >= cnt) return;   // uniform per block

  __shared__ __align__(16) unsigned short xs[TM * XSP];  // 49920 B
  __shared__ __align__(16) unsigned short hs[TM * HSP];  // 13056 B
  __shared__ int   tok_s[TM];
  __shared__ float wt_s[TM];

  const int tid = threadIdx.x;
  if (tid < TM) {
    int idx = start + tid; int t = 0; float w = 0.f;
    if (idx < cnt) {
      if (e == 0) { t = idx; w = (1.f/3.f) * fixed_w[0]; }
      else        { t = tok_list[e*N_TOK + idx]; w = wt_list[e*N_TOK + idx]; }
    }
    tok_s[tid] = t; wt_s[tid] = w;
  }
  __syncthreads();

  // stage x tile bf16 (full K=512): 48 rows x 64 16B-chunks, 6 iters
  for (int i = tid; i < TM * 64; i += 512) {
    const int m = i >> 6, cb = i & 63;
    *(uint4*)(xs + m * XSP + cb * 8) =
        *(const uint4*)(xbf + (size_t)tok_s[m] * DIM + cb * 8);
  }

  const int lane = tid & 63;
  const int w    = tid >> 6;          // 0..7
  const int l15  = lane & 15;
  const int q    = lane >> 4;

  const unsigned short* W1e = W1s + (size_t)e * 128 * 64 * 128;
  const unsigned short* W2e = W2s + (size_t)e * 32 * 256 * 128;

  f32x4 yacc[3][4];
#pragma unroll
  for (int mi = 0; mi < 3; ++mi)
#pragma unroll
    for (int t = 0; t < 4; ++t) yacc[mi][t] = (f32x4){0.f, 0.f, 0.f, 0.f};

  __syncthreads();   // xs ready

  for (int c = half * 8; c < half * 8 + 8; ++c) {
    // ---- phase 1: wave owns n-tile (c*8 + w) of the 128-wide chunk; K=512
    const int nt = c * 8 + w;          // 0..127
    f32x4 hacc[3];
#pragma unroll
    for (int mi = 0; mi < 3; ++mi) hacc[mi] = (f32x4){0.f, 0.f, 0.f, 0.f};
#pragma unroll 4
    for (int s = 0; s < 16; ++s) {
      const bf16x8 a0 = *(const bf16x8*)(xs + l15 * XSP + s * 32 + q * 8);
      const bf16x8 a1 = *(const bf16x8*)(xs + (16 + l15) * XSP + s * 32 + q * 8);
      const bf16x8 a2 = *(const bf16x8*)(xs + (32 + l15) * XSP + s * 32 + q * 8);
      const bf16x8 b = *(const bf16x8*)(
          W1e + ((size_t)nt * 64 + s * 4 + q) * 128 + l15 * 8);
      hacc[0] = __builtin_amdgcn_mfma_f32_16x16x32_bf16(a0, b, hacc[0], 0, 0, 0);
      hacc[1] = __builtin_amdgcn_mfma_f32_16x16x32_bf16(a1, b, hacc[1], 0, 0, 0);
      hacc[2] = __builtin_amdgcn_mfma_f32_16x16x32_bf16(a2, b, hacc[2], 0, 0, 0);
    }
    // bias + relu -> hs (rows = token m, cols = local hidden 0..127)
    {
      const float bv = b1[e * HID + nt * 16 + l15];
      const int col = w * 16 + l15;
#pragma unroll
      for (int mi = 0; mi < 3; ++mi)
#pragma unroll
        for (int reg = 0; reg < 4; ++reg)
          hs[(mi * 16 + q * 4 + reg) * HSP + col] =
              f2bf(fmaxf(hacc[mi][reg] + bv, 0.f));
    }
    __syncthreads();

    // ---- phase 2: wave owns 4 output n-tiles (64 of 512 dims); K=128
#pragma unroll
    for (int s = 0; s < 4; ++s) {
      const bf16x8 a0 = *(const bf16x8*)(hs + l15 * HSP + s * 32 + q * 8);
      const bf16x8 a1 = *(const bf16x8*)(hs + (16 + l15) * HSP + s * 32 + q * 8);
      const bf16x8 a2 = *(const bf16x8*)(hs + (32 + l15) * HSP + s * 32 + q * 8);
      const int kblk = c * 16 + s * 4 + q;
#pragma unroll
      for (int t = 0; t < 4; ++t) {
        const bf16x8 b = *(const bf16x8*)(
            W2e + (((size_t)(w * 4 + t) * 256) + kblk) * 128 + l15 * 8);
        yacc[0][t] = __builtin_amdgcn_mfma_f32_16x16x32_bf16(a0, b, yacc[0][t], 0, 0, 0);
        yacc[1][t] = __builtin_amdgcn_mfma_f32_16x16x32_bf16(a1, b, yacc[1][t], 0, 0, 0);
        yacc[2][t] = __builtin_amdgcn_mfma_f32_16x16x32_bf16(a2, b, yacc[2][t], 0, 0, 0);
      }
    }
    __syncthreads();   // hs consumed before next chunk overwrites
  }

  // ---- epilogue: out[tok] += wt * (y_half + b2*(half==0))
#pragma unroll
  for (int t = 0; t < 4; ++t) {
    const int d = (w * 4 + t) * 16 + l15;
    const float b2v = half ? 0.f : b2[e * DIM + d];
#pragma unroll
    for (int mi = 0; mi < 3; ++mi)
#pragma unroll
      for (int reg = 0; reg < 4; ++reg) {
        const int m = mi * 16 + q * 4 + reg;
        atomicAdd(&out[(size_t)tok_s[m] * DIM + d], wt_s[m] * (yacc[mi][t][reg] + b2v));
      }
  }
}

// ---------------------------------------------------------------------------
// fp32 fallback path (standalone router + mlp) — only if ws_size < WS_REQ
// ---------------------------------------------------------------------------
__global__ __launch_bounds__(256) void router_only(
    const float* __restrict__ x, const float* __restrict__ rW,
    const float* __restrict__ rb, float* __restrict__ out,
    int* __restrict__ cpad, float* __restrict__ ipad, int* __restrict__ done,
    int* __restrict__ tok_list, float* __restrict__ wt_list)
{
  __shared__ float imp_loc[8];
  __shared__ int   cnt_loc[8];
  __shared__ int   ltok[8][32];
  __shared__ float lwt[8][32];
  __shared__ int   base_s[8];

  const int tid = threadIdx.x;
  if (tid < 8) { imp_loc[tid] = 0.f; cnt_loc[tid] = 0; }
  __syncthreads();
  const int wave = tid >> 6, lane = tid & 63;

  for (int it = 0; it < 4; ++it) {
    const int t = blockIdx.x * 16 + wave * 4 + it;
    float xv[8];
#pragma unroll
    for (int j = 0; j < 8; ++j) xv[j] = x[(size_t)t*DIM + lane + 64*j];
    float lg[NC];
#pragma unroll
    for (int e = 0; e < NC; ++e) {
      float s = 0.f;
#pragma unroll
      for (int j = 0; j < 8; ++j) s += xv[j] * rW[(lane + 64*j)*NC + e];
      lg[e] = s;
    }
#pragma unroll
    for (int e = 0; e < NC; ++e) {
      float s = lg[e];
#pragma unroll
      for (int off = 32; off > 0; off >>= 1) s += __shfl_xor(s, off, 64);
      lg[e] = s + rb[e];
    }
    int i1 = 0; float l1 = lg[0];
#pragma unroll
    for (int e = 1; e < NC; ++e) { if (lg[e] > l1) { l1 = lg[e]; i1 = e; } }
    int i2 = -1; float l2 = -3.4e38f;
#pragma unroll
    for (int e = 0; e < NC; ++e) { if (e != i1 && lg[e] > l2) { l2 = lg[e]; i2 = e; } }
    const float ed = expf(l2 - l1);
    const float g1 = 1.f/(1.f+ed), g2 = ed/(1.f+ed);
    float p[NC]; float ssum = 0.f;
#pragma unroll
    for (int e = 0; e < NC; ++e) { p[e] = expf(lg[e] - l1); ssum += p[e]; }
    const float inv = 1.f/ssum;
    if (lane == 0) {
#pragma unroll
      for (int e = 0; e < NC; ++e) atomicAdd(&imp_loc[e], p[e]*inv);
      out[OUT_MIXED + 2 + 2*t]     = (float)(i1 + 1);
      out[OUT_MIXED + 2 + 2*t + 1] = (float)(i2 + 1);
      const int e1 = i1 + 1, e2 = i2 + 1;
      int p1 = atomicAdd(&cnt_loc[e1], 1);
      ltok[e1][p1] = t;  lwt[e1][p1] = (2.f/3.f)*g1;
      int p2 = atomicAdd(&cnt_loc[e2], 1);
      ltok[e2][p2] = t;  lwt[e2][p2] = (2.f/3.f)*g2;
    }
  }
  __syncthreads();
  if (tid >= 1 && tid < 8)
    base_s[tid] = atomicAdd(&cpad[tid * 32], cnt_loc[tid]);
  if (tid < NC)
    atomicAdd(&ipad[(tid + 1) * 32], imp_loc[tid]);
  __syncthreads();
  {
    const int e = tid >> 5, i = tid & 31;
    if (e >= 1 && i < cnt_loc[e]) {
      const int dst = e * N_TOK + base_s[e] + i;
      tok_list[dst] = ltok[e][i];
      wt_list [dst] = lwt[e][i];
    }
  }
  if (tid == 0) {
    __threadfence();
    const int old = atomicAdd(done, 1);
    if (old == 255) {
      __threadfence();
      float lb = 0.f, ent = 0.f;
      for (int e = 0; e < NC; ++e) {
        float p = ipad[(e + 1) * 32] * (1.f/(float)N_TOK);
        float d = p - (1.f/(float)NC);
        lb += d*d;
        ent -= p * logf(fmaxf(p, 1e-8f));
      }
      out[OUT_MIXED]     = lb * (1.f/(float)NC);
      out[OUT_MIXED + 1] = ent;
    }
  }
}

__global__ __launch_bounds__(256) void moe_mlp_kernel(
    const float* __restrict__ x,
    const float* __restrict__ W1, const float* __restrict__ b1,
    const float* __restrict__ W2, const float* __restrict__ b2,
    const float* __restrict__ fixed_w,
    const int* __restrict__ cpad, const int* __restrict__ tok_list,
    const float* __restrict__ wt_list, float* __restrict__ out)
{
  const int e    = blockIdx.x >> 8;
  const int tile = blockIdx.x & 255;
  const int cnt  = (e == 0) ? N_TOK : cpad[e * 32];
  const int start = tile * 16;
  if (start >= cnt) return;

  __shared__ float xs[DIM][17];
  __shared__ float hs2[256][17];
  __shared__ int   tok_s[16];
  __shared__ float wt_s[16];

  const int tid = threadIdx.x;
  if (tid < 16) {
    int idx = start + tid; int t = 0; float w = 0.f;
    if (idx < cnt) {
      if (e == 0) { t = idx; w = (1.f/3.f) * fixed_w[0]; }
      else        { t = tok_list[e*N_TOK + idx]; w = wt_list[e*N_TOK + idx]; }
    }
    tok_s[tid] = t; wt_s[tid] = w;
  }
  __syncthreads();

  for (int i = tid; i < 16*DIM; i += 256) {
    const int m = i >> 9, d = i & (DIM-1);
    xs[d][m] = x[(size_t)tok_s[m]*DIM + d];
  }

  const int r  = tid & 63;
  const int m0 = (tid >> 6) * 4;
  const float* W1e = W1 + (size_t)e * DIM * HID;
  const float* W2e = W2 + (size_t)e * HID * DIM;
  const float* b1e = b1 + e * HID;

  float yacc[4][8];
#pragma unroll
  for (int j = 0; j < 4; ++j)
#pragma unroll
    for (int i = 0; i < 8; ++i) yacc[j][i] = 0.f;

  __syncthreads();

  for (int c = 0; c < 8; ++c) {
    const int k0 = c * 256;
    float bv[4];
#pragma unroll
    for (int i = 0; i < 4; ++i) bv[i] = b1e[k0 + r + 64*i];
    float hacc[4][4];
#pragma unroll
    for (int j = 0; j < 4; ++j)
#pragma unroll
      for (int i = 0; i < 4; ++i) hacc[j][i] = bv[i];
#pragma unroll 2
    for (int d = 0; d < DIM; ++d) {
      float wv[4];
#pragma unroll
      for (int i = 0; i < 4; ++i) wv[i] = W1e[(size_t)d*HID + k0 + r + 64*i];
      float xv[4];
#pragma unroll
      for (int j = 0; j < 4; ++j) xv[j] = xs[d][m0+j];
#pragma unroll
      for (int j = 0; j < 4; ++j)
#pragma unroll
        for (int i = 0; i < 4; ++i) hacc[j][i] += xv[j]*wv[i];
    }
#pragma unroll
    for (int i = 0; i < 4; ++i)
#pragma unroll
      for (int j = 0; j < 4; ++j) hs2[r + 64*i][m0+j] = fmaxf(hacc[j][i], 0.f);
    __syncthreads();

#pragma unroll 2
    for (int k = 0; k < 256; ++k) {
      float wv2[8];
#pragma unroll
      for (int i = 0; i < 8; ++i) wv2[i] = W2e[(size_t)(k0+k)*DIM + r + 64*i];
      float hv[4];
#pragma unroll
      for (int j = 0; j < 4; ++j) hv[j] = hs2[k][m0+j];
#pragma unroll
      for (int j = 0; j < 4; ++j)
#pragma unroll
        for (int i = 0; i < 8; ++i) yacc[j][i] += hv[j]*wv2[i];
    }
    __syncthreads();
  }

#pragma unroll
  for (int i = 0; i < 8; ++i) {
    const int d = r + 64*i;
    const float b2v = b2[e*DIM + d];
#pragma unroll
    for (int j = 0; j < 4; ++j) {
      const int m = m0 + j;
      atomicAdd(&out[(size_t)tok_s[m]*DIM + d], wt_s[m]*(yacc[j][i] + b2v));
    }
  }
}

extern "C" void kernel_launch(void* const* d_in, const int* in_sizes, int n_in,
                              void* d_out, int out_size, void* d_ws, size_t ws_size,
                              hipStream_t stream)
{
  const float* x  = (const float*)d_in[0];
  const float* rW = (const float*)d_in[1];
  const float* rb = (const float*)d_in[2];
  const float* W1 = (const float*)d_in[3];
  const float* b1 = (const float*)d_in[4];
  const float* W2 = (const float*)d_in[5];
  const float* b2 = (const float*)d_in[6];
  const float* fw = (const float*)d_in[7];
  float* out = (float*)d_out;

  int*   cpad     = (int*)d_ws;                          // [e*32], 128B apart
  float* ipad     = (float*)((char*)d_ws + 1024);
  int*   done     = (int*)((char*)d_ws + 2048);
  int*   tok_list = (int*)((char*)d_ws + OFF_TOK);
  float* wt_list  = (float*)((char*)d_ws + OFF_WT);

  hipMemsetAsync(d_ws, 0, 4096, stream);                 // counters + done

  if (ws_size >= WS_REQ) {
    unsigned short* xbf = (unsigned short*)((char*)d_ws + OFF_XBF);
    unsigned int*   W1s = (unsigned int*)((char*)d_ws + OFF_W1S);
    unsigned int*   W2s = (unsigned int*)((char*)d_ws + OFF_W2S);
    prep_kernel<<<3840, 256, 0, stream>>>(x, rW, rb, W1, W2, out,
                                          cpad, ipad, done, tok_list, wt_list,
                                          xbf, W1s, W2s);
    moe_mlp_mfma<<<NEXP*TPE*2, 512, 0, stream>>>(xbf, (const unsigned short*)W1s,
                                                 (const unsigned short*)W2s, b1, b2, fw,
                                                 cpad, tok_list, wt_list, out);
  } else {
    hipMemsetAsync(d_out, 0, (size_t)OUT_MIXED*4, stream);
    router_only<<<256, 256, 0, stream>>>(x, rW, rb, out, cpad, ipad, done,
                                         tok_list, wt_list);
    moe_mlp_kernel<<<NEXP*256, 256, 0, stream>>>(x, W1, b1, W2, b2, fw,
                                                 cpad, tok_list, wt_list, out);
  }
}